// Round 17
// baseline (40.601 us; speedup 1.0000x reference)
//
#include <hip/hip_runtime.h>

// Flash attention fwd, fp32 in/out, f16 MFMA compute, per-batch key masking.
// B=16, LQ=LK=2048, D=64. Swapped QK^T (S^T = K*Q) so softmax is lane-local;
// PV consumes P directly from S^T C-layout registers.
//
// R8  (43.6): reg-staged one-barrier LDS double buffer.
// R14 (41.5): + prepass valid-skip, permuted-V b128 PV, single-split direct out.
// R16 (40.2, best): TPS=8/NSPLIT=4 (fast path valid<=512, combine halved).
// R17: TPS 8->16, NSPLIT 4->2: fast path covers valid<=1024 (~50% of
//      batches), remaining rows have <=2 split slices, 1024 blocks.

namespace {

constexpr int NB  = 16;
constexpr int SLQ = 2048;
constexpr int SLK = 2048;
constexpr int DH  = 64;
constexpr int KB  = 64;   // key tile
constexpr int QB  = 64;   // q rows per block (4 waves x 16)

constexpr int NSPLIT = 2;
constexpr int TPS    = 16;

typedef _Float16 half8  __attribute__((ext_vector_type(8)));
typedef _Float16 half4  __attribute__((ext_vector_type(4)));
typedef _Float16 half2t __attribute__((ext_vector_type(2)));
typedef float    f32x4  __attribute__((ext_vector_type(4)));

__device__ inline half2t pkrtz(float a, float b) {
    return __builtin_bit_cast(half2t, __builtin_amdgcn_cvt_pkrtz(a, b));
}

// ---------------- prepass (R10's, verbatim: valid-skip + permuted V) -----
// K tiles: kws[tile + (rr*8 + (c^(rr&7)))*8 ..+8] = f16(K[b, kt*64+rr, c*8..+8])
// V tiles: key k of d-row at half index d*64 + (p(k) ^ ((d&7)<<3)),
//   p(k)=32(k>>5)+8((k>>2)&3)+4((k>>4)&1)+(k&3)
// so fwd's PV b128 read at (32ss+8g)^swz yields keys {32ss+4g..+3,
// 32ss+16+4g..+3} contiguously (HW-verified in R10).
__global__ __launch_bounds__(256)
void prepass(const float* __restrict__ kg, const float* __restrict__ vg,
             const int* __restrict__ vn,
             _Float16* __restrict__ kws, _Float16* __restrict__ vws)
{
    __shared__ _Float16 VT[DH][72];   // padded transpose staging
    const int t  = threadIdx.x;
    const int b  = blockIdx.x >> 5;
    const int kt = blockIdx.x & 31;
    if (kt * KB >= vn[b]) return;     // tile never consumed
    const size_t tileH = ((size_t)(b << 5) + kt) * 4096;

    // K: thread covers source chunks n=2t, 2t+1 (8 f32 -> 8 f16 each)
    {
        const float* kp = kg + ((size_t)b * SLK + (size_t)kt * KB) * DH + t * 16;
        f32x4 a0 = ((const f32x4*)kp)[0], a1 = ((const f32x4*)kp)[1];
        f32x4 a2 = ((const f32x4*)kp)[2], a3 = ((const f32x4*)kp)[3];
        union { half2t h2[4]; uint4 u; } o0, o1;
        o0.h2[0] = pkrtz(a0[0], a0[1]); o0.h2[1] = pkrtz(a0[2], a0[3]);
        o0.h2[2] = pkrtz(a1[0], a1[1]); o0.h2[3] = pkrtz(a1[2], a1[3]);
        o1.h2[0] = pkrtz(a2[0], a2[1]); o1.h2[1] = pkrtz(a2[2], a2[3]);
        o1.h2[2] = pkrtz(a3[0], a3[1]); o1.h2[3] = pkrtz(a3[2], a3[3]);
#pragma unroll
        for (int j = 0; j < 2; ++j) {
            const int n = 2 * t + j;
            const int rr = n >> 3, c = n & 7;
            const int dst = rr * 8 + (c ^ (rr & 7));
            *(uint4*)(kws + tileH + (size_t)dst * 8) = j ? o1.u : o0.u;
        }
    }
    // V: transpose via LDS, then write in permuted key order (+ bank XOR)
    {
        const int kr = t >> 2, d0 = (t & 3) * 16;
        const float* vp = vg + ((size_t)b * SLK + (size_t)kt * KB + kr) * DH + d0;
        f32x4 a0 = ((const f32x4*)vp)[0], a1 = ((const f32x4*)vp)[1];
        f32x4 a2 = ((const f32x4*)vp)[2], a3 = ((const f32x4*)vp)[3];
#pragma unroll
        for (int i = 0; i < 4; ++i) {
            VT[d0 + i][kr]      = (_Float16)a0[i];
            VT[d0 + 4 + i][kr]  = (_Float16)a1[i];
            VT[d0 + 8 + i][kr]  = (_Float16)a2[i];
            VT[d0 + 12 + i][kr] = (_Float16)a3[i];
        }
    }
    __syncthreads();
#pragma unroll
    for (int j = 0; j < 2; ++j) {
        const int n = 2 * t + j;
        const int d = n >> 3, c = n & 7;     // source keys 8c..8c+7 of row d
        const int rsw = (d & 7) << 3;
        const int pA = 32 * (c >> 2) + 8 * ((2 * c) & 3) + 4 * ((c >> 1) & 1);
        const int pB = 32 * (c >> 2) + 8 * ((2 * c + 1) & 3) + 4 * ((c >> 1) & 1);
        half4 hA = *(const half4*)&VT[d][c * 8];
        half4 hB = *(const half4*)&VT[d][c * 8 + 4];
        *(half4*)(vws + tileH + (size_t)d * 64 + (pA ^ rsw)) = hA;
        *(half4*)(vws + tileH + (size_t)d * 64 + (pB ^ rsw)) = hB;
    }
}

// ---------------- main flash kernel (R16 loop, nsplit=2/TPS=16) -------------
__global__ __launch_bounds__(256)
void attn_fwd(const float* __restrict__ qg, const _Float16* __restrict__ k16,
              const _Float16* __restrict__ v16, const int* __restrict__ vn,
              float* __restrict__ og,
              _Float16* __restrict__ ws_acc, float* __restrict__ ws_ml,
              int nsplit, int tps)
{
    // [buf][ K 4096 halves | V 4096 halves ], 2 buffers = 32 KB
    __shared__ __attribute__((aligned(16))) _Float16 KV[2][8192];

    const int t   = threadIdx.x;
    const int l   = t & 63;
    const int w   = t >> 6;     // wave id 0..3
    const int q15 = l & 15;     // q col within wave's 16 rows (C-layout col)
    const int g   = l >> 4;     // lane group 0..3
    const int swz = (q15 & 7) << 3;

    const int bid = blockIdx.x;
    int b, qt, s;
    if (nsplit == 2) {
        // 1024 blocks; co-resident {bid+256k}: k1=k 0..3, s=k&1 (both splits),
        // b=(hi+k)&15 (4 batches), qt=(bid&15)|((k1>>1)<<4). Bijective.
        const int k1 = bid >> 8;            // 0..3
        s  = k1 & 1;
        b  = (((bid >> 4) & 15) + k1) & 15;
        qt = (bid & 15) | ((k1 >> 1) << 4);
    } else {
        b  = ((bid & 15) + 8 * (bid >> 8)) & 15;
        qt = (bid >> 4) & 31;
        s  = 0;
    }

    const int valid = vn[b];
    const int nkt   = (valid + KB - 1) / KB;
    const int kt0   = s * tps;
    if (kt0 >= nkt) return;                  // block-uniform early out
    const int kt1   = min(nkt, kt0 + tps);
    const int nact  = min(nsplit, (nkt + tps - 1) / tps);

    const int qrow = qt * QB + w * 16 + q15;

    // fold 1/sqrt(D)=1/8 and log2(e) into Q: scores land in log2 units
    const float QS = 0.18033688011112042f;

    half8 qf[2];
    {
        const float* qp = qg + ((size_t)b * SLQ + qrow) * DH;
#pragma unroll
        for (int ss = 0; ss < 2; ++ss) {
            const int d0 = 8 * g + 32 * ss;
            f32x4 x = *(const f32x4*)(qp + d0);
            f32x4 y = *(const f32x4*)(qp + d0 + 4);
            half8 h;
#pragma unroll
            for (int i = 0; i < 4; ++i) {
                h[i]     = (_Float16)(x[i] * QS);
                h[i + 4] = (_Float16)(y[i] * QS);
            }
            qf[ss] = h;
        }
    }

    f32x4 acc[4];
#pragma unroll
    for (int i = 0; i < 4; ++i) acc[i] = f32x4{0.f, 0.f, 0.f, 0.f};
    float m = -1e30f, lsum = 0.f;

    const _Float16* kbase = k16 + (size_t)(b << 5) * 4096;
    const _Float16* vbase = v16 + (size_t)(b << 5) * 4096;

    // reg staging: thread t owns chunks t and t+256 of each tile
    uint4 rk0, rk1, rv0, rv1;
#define LOADREGS(KT)                                                         \
    {                                                                        \
        const uint4* kp_ = (const uint4*)(kbase + (size_t)(KT) * 4096);      \
        const uint4* vp_ = (const uint4*)(vbase + (size_t)(KT) * 4096);      \
        rk0 = kp_[t]; rk1 = kp_[t + 256];                                    \
        rv0 = vp_[t]; rv1 = vp_[t + 256];                                    \
    }
#define WRITEKV(CUR)                                                         \
    {                                                                        \
        uint4* kl_ = (uint4*)&KV[CUR][0];                                    \
        uint4* vl_ = (uint4*)&KV[CUR][4096];                                 \
        kl_[t] = rk0; kl_[t + 256] = rk1;                                    \
        vl_[t] = rv0; vl_[t + 256] = rv1;                                    \
    }

    LOADREGS(kt0);
    int cur = 0;

    for (int kt = kt0; kt < kt1; ++kt) {
        // write staged regs to buf[cur]; then issue next tile's global loads
        // (regs only, no LDS hazard); barrier publishes writes + fences
        // prior readers of buf[cur].
        WRITEKV(cur);
        const bool more = (kt + 1 < kt1);
        if (more) LOADREGS(kt + 1);
        __syncthreads();

        const _Float16* Kc = &KV[cur][0];
        const _Float16* Vc = &KV[cur][4096];

        // ---- QK^T (swapped): st[mt] C-layout: col=q15, row=key 16mt+4g+r
        f32x4 st[4];
#pragma unroll
        for (int mt = 0; mt < 4; ++mt) {
            f32x4 c = f32x4{0.f, 0.f, 0.f, 0.f};
#pragma unroll
            for (int ss = 0; ss < 2; ++ss) {
                half8 a = *(const half8*)&Kc[(16 * mt + q15) * 64 + ((8 * g + 32 * ss) ^ swz)];
                c = __builtin_amdgcn_mfma_f32_16x16x32_f16(a, qf[ss], c, 0, 0, 0);
            }
            st[mt] = c;
        }

        // ---- mask the (only) partial boundary tile
        const int krem = valid - kt * KB;
        if (krem < KB) {
#pragma unroll
            for (int mt = 0; mt < 4; ++mt)
#pragma unroll
                for (int r = 0; r < 4; ++r)
                    if (16 * mt + 4 * g + r >= krem) st[mt][r] = -1e30f;
        }

        // ---- tile max: pairwise tree (short dep chain)
        float x0 = fmaxf(fmaxf(st[0][0], st[0][1]), fmaxf(st[0][2], st[0][3]));
        float x1 = fmaxf(fmaxf(st[1][0], st[1][1]), fmaxf(st[1][2], st[1][3]));
        float x2 = fmaxf(fmaxf(st[2][0], st[2][1]), fmaxf(st[2][2], st[2][3]));
        float x3 = fmaxf(fmaxf(st[3][0], st[3][1]), fmaxf(st[3][2], st[3][3]));
        float tmax = fmaxf(fmaxf(x0, x1), fmaxf(x2, x3));
        tmax = fmaxf(tmax, __shfl_xor(tmax, 16));
        tmax = fmaxf(tmax, __shfl_xor(tmax, 32));

        // ---- T13 defer-max: skip rescale while growth <= 12 (P<=2^12 f16-safe)
        if (!__all(tmax - m <= 12.0f)) {
            const float mn = fmaxf(m, tmax);
            const float sc = __builtin_amdgcn_exp2f(m - mn);
            lsum *= sc;
#pragma unroll
            for (int mt = 0; mt < 4; ++mt) acc[mt] *= sc;
            m = mn;
        }

        float p[4][4];
#pragma unroll
        for (int mt = 0; mt < 4; ++mt)
#pragma unroll
            for (int r = 0; r < 4; ++r)
                p[mt][r] = __builtin_amdgcn_exp2f(st[mt][r] - m);

        // pairwise sum tree
        float s0 = (p[0][0] + p[0][1]) + (p[0][2] + p[0][3]);
        float s1 = (p[1][0] + p[1][1]) + (p[1][2] + p[1][3]);
        float s2 = (p[2][0] + p[2][1]) + (p[2][2] + p[2][3]);
        float s3 = (p[3][0] + p[3][1]) + (p[3][2] + p[3][3]);
        float ps = (s0 + s1) + (s2 + s3);
        ps += __shfl_xor(ps, 16);
        ps += __shfl_xor(ps, 32);
        lsum += ps;

        half2t pk[4][2];
#pragma unroll
        for (int mt = 0; mt < 4; ++mt)
#pragma unroll
            for (int rr = 0; rr < 2; ++rr)
                pk[mt][rr] = pkrtz(p[mt][2 * rr], p[mt][2 * rr + 1]);

        // ---- PV: b128 V reads (permuted layout), slot-consistent
#pragma unroll
        for (int ss = 0; ss < 2; ++ss) {
            union { half2t h2[4]; half8 v; } bf;
            bf.h2[0] = pk[2 * ss][0];
            bf.h2[1] = pk[2 * ss][1];
            bf.h2[2] = pk[2 * ss + 1][0];
            bf.h2[3] = pk[2 * ss + 1][1];
#pragma unroll
            for (int mt = 0; mt < 4; ++mt) {
                half8 af = *(const half8*)&Vc[(16 * mt + q15) * 64 + ((32 * ss + 8 * g) ^ swz)];
                acc[mt] = __builtin_amdgcn_mfma_f32_16x16x32_f16(af, bf.v, acc[mt], 0, 0, 0);
            }
        }
        cur ^= 1;
    }
#undef LOADREGS
#undef WRITEKV

    if (nact == 1) {
        // ---- single-split fast path: write normalized fp32 out directly
        const float inv = 1.0f / lsum;
        float* op = og + ((size_t)b * SLQ + qrow) * DH;
#pragma unroll
        for (int mt = 0; mt < 4; ++mt) {
            f32x4 o;
#pragma unroll
            for (int r = 0; r < 4; ++r) o[r] = acc[mt][r] * inv;
            *(f32x4*)(op + 16 * mt + 4 * g) = o;
        }
        return;
    }

    // ---- split epilogue: normalized f16 acc + (m,l) to workspace
    const float inv = 1.0f / lsum;
    const size_t row = (size_t)b * SLQ + qrow;
    _Float16* wp = ws_acc + ((size_t)s * NB * SLQ + row) * DH;
#pragma unroll
    for (int mt = 0; mt < 4; ++mt) {
        union { half2t h2[2]; uint2 u; } o;
        o.h2[0] = pkrtz(acc[mt][0] * inv, acc[mt][1] * inv);
        o.h2[1] = pkrtz(acc[mt][2] * inv, acc[mt][3] * inv);
        *(uint2*)(wp + 16 * mt + 4 * g) = o.u;
    }
    if (g == 0)
        *(float2*)(ws_ml + ((size_t)s * NB * SLQ + row) * 2) = make_float2(m, lsum);
}

// ---------------- combine ----------------------------------------------------
__global__ __launch_bounds__(256)
void attn_combine(const _Float16* __restrict__ ws_acc, const float* __restrict__ ws_ml,
                  const int* __restrict__ vn, float* __restrict__ og,
                  int nsplit, int tps)
{
    const int tid = blockIdx.x * 256 + threadIdx.x;
    const int row = tid >> 2;
    const int dq  = (tid & 3) << 4;
    const int b   = row >> 11;

    const int valid = vn[b];
    const int nkt   = (valid + KB - 1) / KB;
    const int nact  = min(nsplit, (nkt + tps - 1) / tps);
    if (nact <= 1) return;   // fwd wrote these rows directly

    float M = -1e30f;
    for (int s = 0; s < nact; ++s)
        M = fmaxf(M, ws_ml[((size_t)s * NB * SLQ + row) * 2]);

    float L = 0.f;
    f32x4 o[4];
#pragma unroll
    for (int i = 0; i < 4; ++i) o[i] = f32x4{0.f, 0.f, 0.f, 0.f};

    for (int s = 0; s < nact; ++s) {
        const float2 ml = *(const float2*)(ws_ml + ((size_t)s * NB * SLQ + row) * 2);
        const float wl = __builtin_amdgcn_exp2f(ml.x - M) * ml.y;  // weight * l_s
        L += wl;
        const _Float16* ap = ws_acc + ((size_t)s * NB * SLQ + row) * DH + dq;
        half8 h0 = ((const half8*)ap)[0];
        half8 h1 = ((const half8*)ap)[1];
#pragma unroll
        for (int r = 0; r < 4; ++r) {
            o[0][r] += wl * (float)h0[r];
            o[1][r] += wl * (float)h0[4 + r];
            o[2][r] += wl * (float)h1[r];
            o[3][r] += wl * (float)h1[4 + r];
        }
    }

    const float inv = 1.0f / L;
    float* op = og + (size_t)row * DH + dq;
#pragma unroll
    for (int i = 0; i < 4; ++i) {
        f32x4 r = o[i] * inv;
        *(f32x4*)(op + 4 * i) = r;
    }
}

} // namespace

extern "C" void kernel_launch(void* const* d_in, const int* in_sizes, int n_in,
                              void* d_out, int out_size, void* d_ws, size_t ws_size,
                              hipStream_t stream)
{
    const float* q    = (const float*)d_in[0];
    const float* k    = (const float*)d_in[1];
    const float* v    = (const float*)d_in[2];
    const int*   vnum = (const int*)d_in[3];
    float* out = (float*)d_out;

    const size_t k16H  = (size_t)NB * SLK * DH;         // 2.10M halves (4 MB)
    const size_t v16H  = k16H;
    const size_t rowsH = (size_t)NB * SLQ;              // 32768 q-rows

    // choose split count by workspace budget (~17.3 MB for nsplit=2)
    int nsplit = NSPLIT;
    {
        const size_t need = (k16H + v16H + (size_t)NSPLIT * rowsH * DH) * 2
                          + (size_t)NSPLIT * rowsH * 2 * 4;
        if (ws_size < need) nsplit = 1;                 // fallback
    }
    const int tps = (nsplit == NSPLIT) ? TPS : 32;

    _Float16* k16    = (_Float16*)d_ws;
    _Float16* v16t   = k16 + k16H;
    _Float16* ws_acc = v16t + v16H;
    float*    ws_ml  = (float*)(ws_acc + (size_t)nsplit * rowsH * DH);

    prepass<<<dim3(NB * (SLK / KB)), dim3(256), 0, stream>>>(k, v, vnum, k16, v16t);

    dim3 gfwd(nsplit == NSPLIT ? 1024 : 512);
    attn_fwd<<<gfwd, dim3(256), 0, stream>>>(q, k16, v16t, vnum, out,
                                             ws_acc, ws_ml, nsplit, tps);

    attn_combine<<<dim3((NB * SLQ * 4) / 256), dim3(256), 0, stream>>>(
        ws_acc, ws_ml, vnum, out, nsplit, tps);
}

// Round 18
// 39.926 us; speedup vs baseline: 1.0169x; 1.0169x over previous
//
#include <hip/hip_runtime.h>

// Flash attention fwd, fp32 in/out, f16 MFMA compute, per-batch key masking.
// B=16, LQ=LK=2048, D=64. Swapped QK^T (S^T = K*Q) so softmax is lane-local;
// PV consumes P directly from S^T C-layout registers.
//
// Final configuration (= R16, measured best 40.16us):
//   - prepass: K/V -> f16 tiles (valid-skip; V transposed + permuted so PV
//     reads are b128; LDS bank-XOR baked into layout)  [HW-verified R8/R10]
//   - fwd: reg-staged one-barrier LDS double buffer, QB=64, NSPLIT=4/TPS=8,
//     2048 blocks, split/batch-diverse co-resident mapping, pairwise trees,
//     T13 defer-max, single-split direct fp32 out.
//   - combine: separate kernel (no fences), early-out for direct-out rows.
// Granularity sweep bracketed: TPS=4 (41.5) / TPS=8 (40.16) / TPS=16 (40.6).
// Rejected by measurement: fused-combine fences (R11, 3x), no-LDS loop (R12),
// dynamic work queue (R13), setprio (R15), load-hoist (R15).

namespace {

constexpr int NB  = 16;
constexpr int SLQ = 2048;
constexpr int SLK = 2048;
constexpr int DH  = 64;
constexpr int KB  = 64;   // key tile
constexpr int QB  = 64;   // q rows per block (4 waves x 16)

constexpr int NSPLIT = 4;
constexpr int TPS    = 8;

typedef _Float16 half8  __attribute__((ext_vector_type(8)));
typedef _Float16 half4  __attribute__((ext_vector_type(4)));
typedef _Float16 half2t __attribute__((ext_vector_type(2)));
typedef float    f32x4  __attribute__((ext_vector_type(4)));

__device__ inline half2t pkrtz(float a, float b) {
    return __builtin_bit_cast(half2t, __builtin_amdgcn_cvt_pkrtz(a, b));
}

// ---------------- prepass -----------------------------------------------
// K tiles: kws[tile + (rr*8 + (c^(rr&7)))*8 ..+8] = f16(K[b, kt*64+rr, c*8..+8])
// V tiles: key k of d-row at half index d*64 + (p(k) ^ ((d&7)<<3)),
//   p(k)=32(k>>5)+8((k>>2)&3)+4((k>>4)&1)+(k&3)
// so fwd's PV b128 read at (32ss+8g)^swz yields keys {32ss+4g..+3,
// 32ss+16+4g..+3} contiguously (HW-verified in R10).
__global__ __launch_bounds__(256)
void prepass(const float* __restrict__ kg, const float* __restrict__ vg,
             const int* __restrict__ vn,
             _Float16* __restrict__ kws, _Float16* __restrict__ vws)
{
    __shared__ _Float16 VT[DH][72];   // padded transpose staging
    const int t  = threadIdx.x;
    const int b  = blockIdx.x >> 5;
    const int kt = blockIdx.x & 31;
    if (kt * KB >= vn[b]) return;     // tile never consumed
    const size_t tileH = ((size_t)(b << 5) + kt) * 4096;

    // K: thread covers source chunks n=2t, 2t+1 (8 f32 -> 8 f16 each)
    {
        const float* kp = kg + ((size_t)b * SLK + (size_t)kt * KB) * DH + t * 16;
        f32x4 a0 = ((const f32x4*)kp)[0], a1 = ((const f32x4*)kp)[1];
        f32x4 a2 = ((const f32x4*)kp)[2], a3 = ((const f32x4*)kp)[3];
        union { half2t h2[4]; uint4 u; } o0, o1;
        o0.h2[0] = pkrtz(a0[0], a0[1]); o0.h2[1] = pkrtz(a0[2], a0[3]);
        o0.h2[2] = pkrtz(a1[0], a1[1]); o0.h2[3] = pkrtz(a1[2], a1[3]);
        o1.h2[0] = pkrtz(a2[0], a2[1]); o1.h2[1] = pkrtz(a2[2], a2[3]);
        o1.h2[2] = pkrtz(a3[0], a3[1]); o1.h2[3] = pkrtz(a3[2], a3[3]);
#pragma unroll
        for (int j = 0; j < 2; ++j) {
            const int n = 2 * t + j;
            const int rr = n >> 3, c = n & 7;
            const int dst = rr * 8 + (c ^ (rr & 7));
            *(uint4*)(kws + tileH + (size_t)dst * 8) = j ? o1.u : o0.u;
        }
    }
    // V: transpose via LDS, then write in permuted key order (+ bank XOR)
    {
        const int kr = t >> 2, d0 = (t & 3) * 16;
        const float* vp = vg + ((size_t)b * SLK + (size_t)kt * KB + kr) * DH + d0;
        f32x4 a0 = ((const f32x4*)vp)[0], a1 = ((const f32x4*)vp)[1];
        f32x4 a2 = ((const f32x4*)vp)[2], a3 = ((const f32x4*)vp)[3];
#pragma unroll
        for (int i = 0; i < 4; ++i) {
            VT[d0 + i][kr]      = (_Float16)a0[i];
            VT[d0 + 4 + i][kr]  = (_Float16)a1[i];
            VT[d0 + 8 + i][kr]  = (_Float16)a2[i];
            VT[d0 + 12 + i][kr] = (_Float16)a3[i];
        }
    }
    __syncthreads();
#pragma unroll
    for (int j = 0; j < 2; ++j) {
        const int n = 2 * t + j;
        const int d = n >> 3, c = n & 7;     // source keys 8c..8c+7 of row d
        const int rsw = (d & 7) << 3;
        const int pA = 32 * (c >> 2) + 8 * ((2 * c) & 3) + 4 * ((c >> 1) & 1);
        const int pB = 32 * (c >> 2) + 8 * ((2 * c + 1) & 3) + 4 * ((c >> 1) & 1);
        half4 hA = *(const half4*)&VT[d][c * 8];
        half4 hB = *(const half4*)&VT[d][c * 8 + 4];
        *(half4*)(vws + tileH + (size_t)d * 64 + (pA ^ rsw)) = hA;
        *(half4*)(vws + tileH + (size_t)d * 64 + (pB ^ rsw)) = hB;
    }
}

// ---------------- main flash kernel (nsplit=4/TPS=8) ------------------------
__global__ __launch_bounds__(256)
void attn_fwd(const float* __restrict__ qg, const _Float16* __restrict__ k16,
              const _Float16* __restrict__ v16, const int* __restrict__ vn,
              float* __restrict__ og,
              _Float16* __restrict__ ws_acc, float* __restrict__ ws_ml,
              int nsplit, int tps)
{
    // [buf][ K 4096 halves | V 4096 halves ], 2 buffers = 32 KB
    __shared__ __attribute__((aligned(16))) _Float16 KV[2][8192];

    const int t   = threadIdx.x;
    const int l   = t & 63;
    const int w   = t >> 6;     // wave id 0..3
    const int q15 = l & 15;     // q col within wave's 16 rows (C-layout col)
    const int g   = l >> 4;     // lane group 0..3
    const int swz = (q15 & 7) << 3;

    const int bid = blockIdx.x;
    int b, qt, s;
    if (nsplit == 4) {
        // 2048 blocks; co-resident {bid+256k}: k2=k 0..7, s=k&3 (all splits),
        // b=(hi+k)&15 (8 batches), qt=(bid&15)|((k2>>2)<<4). Bijective.
        const int k2 = bid >> 8;            // 0..7
        s  = k2 & 3;
        b  = (((bid >> 4) & 15) + k2) & 15;
        qt = (bid & 15) | ((k2 >> 2) << 4);
    } else {
        b  = ((bid & 15) + 8 * (bid >> 8)) & 15;
        qt = (bid >> 4) & 31;
        s  = 0;
    }

    const int valid = vn[b];
    const int nkt   = (valid + KB - 1) / KB;
    const int kt0   = s * tps;
    if (kt0 >= nkt) return;                  // block-uniform early out
    const int kt1   = min(nkt, kt0 + tps);
    const int nact  = min(nsplit, (nkt + tps - 1) / tps);

    const int qrow = qt * QB + w * 16 + q15;

    // fold 1/sqrt(D)=1/8 and log2(e) into Q: scores land in log2 units
    const float QS = 0.18033688011112042f;

    half8 qf[2];
    {
        const float* qp = qg + ((size_t)b * SLQ + qrow) * DH;
#pragma unroll
        for (int ss = 0; ss < 2; ++ss) {
            const int d0 = 8 * g + 32 * ss;
            f32x4 x = *(const f32x4*)(qp + d0);
            f32x4 y = *(const f32x4*)(qp + d0 + 4);
            half8 h;
#pragma unroll
            for (int i = 0; i < 4; ++i) {
                h[i]     = (_Float16)(x[i] * QS);
                h[i + 4] = (_Float16)(y[i] * QS);
            }
            qf[ss] = h;
        }
    }

    f32x4 acc[4];
#pragma unroll
    for (int i = 0; i < 4; ++i) acc[i] = f32x4{0.f, 0.f, 0.f, 0.f};
    float m = -1e30f, lsum = 0.f;

    const _Float16* kbase = k16 + (size_t)(b << 5) * 4096;
    const _Float16* vbase = v16 + (size_t)(b << 5) * 4096;

    // reg staging: thread t owns chunks t and t+256 of each tile
    uint4 rk0, rk1, rv0, rv1;
#define LOADREGS(KT)                                                         \
    {                                                                        \
        const uint4* kp_ = (const uint4*)(kbase + (size_t)(KT) * 4096);      \
        const uint4* vp_ = (const uint4*)(vbase + (size_t)(KT) * 4096);      \
        rk0 = kp_[t]; rk1 = kp_[t + 256];                                    \
        rv0 = vp_[t]; rv1 = vp_[t + 256];                                    \
    }
#define WRITEKV(CUR)                                                         \
    {                                                                        \
        uint4* kl_ = (uint4*)&KV[CUR][0];                                    \
        uint4* vl_ = (uint4*)&KV[CUR][4096];                                 \
        kl_[t] = rk0; kl_[t + 256] = rk1;                                    \
        vl_[t] = rv0; vl_[t + 256] = rv1;                                    \
    }

    LOADREGS(kt0);
    int cur = 0;

    for (int kt = kt0; kt < kt1; ++kt) {
        // write staged regs to buf[cur]; then issue next tile's global loads
        // (regs only, no LDS hazard); barrier publishes writes + fences
        // prior readers of buf[cur].
        WRITEKV(cur);
        const bool more = (kt + 1 < kt1);
        if (more) LOADREGS(kt + 1);
        __syncthreads();

        const _Float16* Kc = &KV[cur][0];
        const _Float16* Vc = &KV[cur][4096];

        // ---- QK^T (swapped): st[mt] C-layout: col=q15, row=key 16mt+4g+r
        f32x4 st[4];
#pragma unroll
        for (int mt = 0; mt < 4; ++mt) {
            f32x4 c = f32x4{0.f, 0.f, 0.f, 0.f};
#pragma unroll
            for (int ss = 0; ss < 2; ++ss) {
                half8 a = *(const half8*)&Kc[(16 * mt + q15) * 64 + ((8 * g + 32 * ss) ^ swz)];
                c = __builtin_amdgcn_mfma_f32_16x16x32_f16(a, qf[ss], c, 0, 0, 0);
            }
            st[mt] = c;
        }

        // ---- mask the (only) partial boundary tile
        const int krem = valid - kt * KB;
        if (krem < KB) {
#pragma unroll
            for (int mt = 0; mt < 4; ++mt)
#pragma unroll
                for (int r = 0; r < 4; ++r)
                    if (16 * mt + 4 * g + r >= krem) st[mt][r] = -1e30f;
        }

        // ---- tile max: pairwise tree (short dep chain)
        float x0 = fmaxf(fmaxf(st[0][0], st[0][1]), fmaxf(st[0][2], st[0][3]));
        float x1 = fmaxf(fmaxf(st[1][0], st[1][1]), fmaxf(st[1][2], st[1][3]));
        float x2 = fmaxf(fmaxf(st[2][0], st[2][1]), fmaxf(st[2][2], st[2][3]));
        float x3 = fmaxf(fmaxf(st[3][0], st[3][1]), fmaxf(st[3][2], st[3][3]));
        float tmax = fmaxf(fmaxf(x0, x1), fmaxf(x2, x3));
        tmax = fmaxf(tmax, __shfl_xor(tmax, 16));
        tmax = fmaxf(tmax, __shfl_xor(tmax, 32));

        // ---- T13 defer-max: skip rescale while growth <= 12 (P<=2^12 f16-safe)
        if (!__all(tmax - m <= 12.0f)) {
            const float mn = fmaxf(m, tmax);
            const float sc = __builtin_amdgcn_exp2f(m - mn);
            lsum *= sc;
#pragma unroll
            for (int mt = 0; mt < 4; ++mt) acc[mt] *= sc;
            m = mn;
        }

        float p[4][4];
#pragma unroll
        for (int mt = 0; mt < 4; ++mt)
#pragma unroll
            for (int r = 0; r < 4; ++r)
                p[mt][r] = __builtin_amdgcn_exp2f(st[mt][r] - m);

        // pairwise sum tree
        float s0 = (p[0][0] + p[0][1]) + (p[0][2] + p[0][3]);
        float s1 = (p[1][0] + p[1][1]) + (p[1][2] + p[1][3]);
        float s2 = (p[2][0] + p[2][1]) + (p[2][2] + p[2][3]);
        float s3 = (p[3][0] + p[3][1]) + (p[3][2] + p[3][3]);
        float ps = (s0 + s1) + (s2 + s3);
        ps += __shfl_xor(ps, 16);
        ps += __shfl_xor(ps, 32);
        lsum += ps;

        half2t pk[4][2];
#pragma unroll
        for (int mt = 0; mt < 4; ++mt)
#pragma unroll
            for (int rr = 0; rr < 2; ++rr)
                pk[mt][rr] = pkrtz(p[mt][2 * rr], p[mt][2 * rr + 1]);

        // ---- PV: b128 V reads (permuted layout), slot-consistent
#pragma unroll
        for (int ss = 0; ss < 2; ++ss) {
            union { half2t h2[4]; half8 v; } bf;
            bf.h2[0] = pk[2 * ss][0];
            bf.h2[1] = pk[2 * ss][1];
            bf.h2[2] = pk[2 * ss + 1][0];
            bf.h2[3] = pk[2 * ss + 1][1];
#pragma unroll
            for (int mt = 0; mt < 4; ++mt) {
                half8 af = *(const half8*)&Vc[(16 * mt + q15) * 64 + ((32 * ss + 8 * g) ^ swz)];
                acc[mt] = __builtin_amdgcn_mfma_f32_16x16x32_f16(af, bf.v, acc[mt], 0, 0, 0);
            }
        }
        cur ^= 1;
    }
#undef LOADREGS
#undef WRITEKV

    if (nact == 1) {
        // ---- single-split fast path: write normalized fp32 out directly
        const float inv = 1.0f / lsum;
        float* op = og + ((size_t)b * SLQ + qrow) * DH;
#pragma unroll
        for (int mt = 0; mt < 4; ++mt) {
            f32x4 o;
#pragma unroll
            for (int r = 0; r < 4; ++r) o[r] = acc[mt][r] * inv;
            *(f32x4*)(op + 16 * mt + 4 * g) = o;
        }
        return;
    }

    // ---- split epilogue: normalized f16 acc + (m,l) to workspace
    const float inv = 1.0f / lsum;
    const size_t row = (size_t)b * SLQ + qrow;
    _Float16* wp = ws_acc + ((size_t)s * NB * SLQ + row) * DH;
#pragma unroll
    for (int mt = 0; mt < 4; ++mt) {
        union { half2t h2[2]; uint2 u; } o;
        o.h2[0] = pkrtz(acc[mt][0] * inv, acc[mt][1] * inv);
        o.h2[1] = pkrtz(acc[mt][2] * inv, acc[mt][3] * inv);
        *(uint2*)(wp + 16 * mt + 4 * g) = o.u;
    }
    if (g == 0)
        *(float2*)(ws_ml + ((size_t)s * NB * SLQ + row) * 2) = make_float2(m, lsum);
}

// ---------------- combine ----------------------------------------------------
__global__ __launch_bounds__(256)
void attn_combine(const _Float16* __restrict__ ws_acc, const float* __restrict__ ws_ml,
                  const int* __restrict__ vn, float* __restrict__ og,
                  int nsplit, int tps)
{
    const int tid = blockIdx.x * 256 + threadIdx.x;
    const int row = tid >> 2;
    const int dq  = (tid & 3) << 4;
    const int b   = row >> 11;

    const int valid = vn[b];
    const int nkt   = (valid + KB - 1) / KB;
    const int nact  = min(nsplit, (nkt + tps - 1) / tps);
    if (nact <= 1) return;   // fwd wrote these rows directly

    float M = -1e30f;
    for (int s = 0; s < nact; ++s)
        M = fmaxf(M, ws_ml[((size_t)s * NB * SLQ + row) * 2]);

    float L = 0.f;
    f32x4 o[4];
#pragma unroll
    for (int i = 0; i < 4; ++i) o[i] = f32x4{0.f, 0.f, 0.f, 0.f};

    for (int s = 0; s < nact; ++s) {
        const float2 ml = *(const float2*)(ws_ml + ((size_t)s * NB * SLQ + row) * 2);
        const float wl = __builtin_amdgcn_exp2f(ml.x - M) * ml.y;  // weight * l_s
        L += wl;
        const _Float16* ap = ws_acc + ((size_t)s * NB * SLQ + row) * DH + dq;
        half8 h0 = ((const half8*)ap)[0];
        half8 h1 = ((const half8*)ap)[1];
#pragma unroll
        for (int r = 0; r < 4; ++r) {
            o[0][r] += wl * (float)h0[r];
            o[1][r] += wl * (float)h0[4 + r];
            o[2][r] += wl * (float)h1[r];
            o[3][r] += wl * (float)h1[4 + r];
        }
    }

    const float inv = 1.0f / L;
    float* op = og + (size_t)row * DH + dq;
#pragma unroll
    for (int i = 0; i < 4; ++i) {
        f32x4 r = o[i] * inv;
        *(f32x4*)(op + 4 * i) = r;
    }
}

} // namespace

extern "C" void kernel_launch(void* const* d_in, const int* in_sizes, int n_in,
                              void* d_out, int out_size, void* d_ws, size_t ws_size,
                              hipStream_t stream)
{
    const float* q    = (const float*)d_in[0];
    const float* k    = (const float*)d_in[1];
    const float* v    = (const float*)d_in[2];
    const int*   vnum = (const int*)d_in[3];
    float* out = (float*)d_out;

    const size_t k16H  = (size_t)NB * SLK * DH;         // 2.10M halves (4 MB)
    const size_t v16H  = k16H;
    const size_t rowsH = (size_t)NB * SLQ;              // 32768 q-rows

    // choose split count by workspace budget (~26 MB for nsplit=4)
    int nsplit = NSPLIT;
    {
        const size_t need = (k16H + v16H + (size_t)NSPLIT * rowsH * DH) * 2
                          + (size_t)NSPLIT * rowsH * 2 * 4;
        if (ws_size < need) nsplit = 1;                 // fallback
    }
    const int tps = (nsplit == NSPLIT) ? TPS : 32;

    _Float16* k16    = (_Float16*)d_ws;
    _Float16* v16t   = k16 + k16H;
    _Float16* ws_acc = v16t + v16H;
    float*    ws_ml  = (float*)(ws_acc + (size_t)nsplit * rowsH * DH);

    prepass<<<dim3(NB * (SLK / KB)), dim3(256), 0, stream>>>(k, v, vnum, k16, v16t);

    dim3 gfwd(nsplit == NSPLIT ? 2048 : 512);
    attn_fwd<<<gfwd, dim3(256), 0, stream>>>(q, k16, v16t, vnum, out,
                                             ws_acc, ws_ml, nsplit, tps);

    attn_combine<<<dim3((NB * SLQ * 4) / 256), dim3(256), 0, stream>>>(
        ws_acc, ws_ml, vnum, out, nsplit, tps);
}